// Round 1
// baseline (6781.625 us; speedup 1.0000x reference)
//
#include <hip/hip_runtime.h>
#include <hip/hip_bf16.h>

// Persistent-weights LSTM for MI355X.  B=32, T=1024, D_IN=512, H=512.
// 64 WGs x 256 threads, all co-resident. Each WG owns 8 h-cols x 4 gates;
// its [1024 x 32] f16 weight slice lives in VGPRs (128/lane) all run.
//
// R5: sentinel handshake + packed records.
//   - Data records are pure payload: 4xf16 per 8B slot (no epoch) ->
//     h A-fragment assembly is 32 coalesced 8B loads (was 64), and each
//     u64 pair aliases directly onto a half8 MFMA operand.
//   - Validity lives in per-(WG,wave) sentinels: producer wave stores its
//     16 records (relaxed agent), then lane 0 does ONE __ATOMIC_RELEASE
//     agent store of the epoch. The release's wave-wide s_waitcnt vmcnt(0)
//     orders records-before-sentinel at the LLC.
//   - Consumer spin is CHEAP: wave needs records only from producer waves
//     {mt*2, mt*2+1} of all 64 WGs = 128 sentinels; 2 per lane -> one
//     attempt = 2 coalesced 8B loads + 2 cmps + __all (was 64 loads +
//     ~200 VALU of epoch checks). After the spin passes, data loads are
//     issued exactly once, unvalidated.
// Overwrite throttling (why epoch-less records are safe): sentinel E+1
// from ANY wave of WG Z implies Z passed its step-(E-1) __syncthreads,
// hence ALL Z's waves finished loading epoch-(E-1) data. Writers of epoch
// E+1/E+2 records are gated on spin(E-1)/spin(E), so no record is ever
// clobbered mid-read. (This argument REQUIRES the per-step __syncthreads.)
// Exact-match epochs keep the 0xAA ws poison harmless (never == target).

#define T_STEPS 1024
#define BATCH   32
#define DIN     512
#define H       512
#define NWG     64
#define HC      8
#define XSTRIDE 520        // f16 elems; 1040B row = bank offset 4 -> 2-way max (free)
#define GSTRIDE 34         // padded f32 row stride of LDS gate tile
#define RECS_PER_PARITY 4096   // 16 kk * 2 s * 128  (4xf16 payload records)
#define SENT_PER_PARITY 256    // 4 producer waves * 64 WGs

typedef _Float16 half8  __attribute__((ext_vector_type(8)));
typedef _Float16 half4v __attribute__((ext_vector_type(4)));
typedef float    f32x4  __attribute__((ext_vector_type(4)));
typedef unsigned long long u64;
typedef unsigned int       u32;

#define AT_LD_U64(p)       __hip_atomic_load((const u64*)(p), __ATOMIC_RELAXED, __HIP_MEMORY_SCOPE_AGENT)
#define AT_ST_U64(p,v)     __hip_atomic_store((u64*)(p), (v), __ATOMIC_RELAXED, __HIP_MEMORY_SCOPE_AGENT)
#define AT_ST_REL_U64(p,v) __hip_atomic_store((u64*)(p), (v), __ATOMIC_RELEASE, __HIP_MEMORY_SCOPE_AGENT)

__device__ __forceinline__ float sigmoidf_(float x) {
    return 1.0f / (1.0f + __expf(-x));
}
__device__ __forceinline__ float tanhf_(float x) {
    return 1.0f - 2.0f / (1.0f + __expf(2.0f * x));
}

__global__ __launch_bounds__(256, 1) void lstm_persistent(
    const float* __restrict__ x,
    const float* __restrict__ init_states,
    const float* __restrict__ Wi, const float* __restrict__ Ui, const float* __restrict__ bi,
    const float* __restrict__ Wf, const float* __restrict__ Uf, const float* __restrict__ bf,
    const float* __restrict__ Wc, const float* __restrict__ Uc, const float* __restrict__ bc,
    const float* __restrict__ Wo, const float* __restrict__ Uo, const float* __restrict__ bo,
    float* __restrict__ out,
    u64* __restrict__ hrec)    // [2 x 4096 records][2 x 256 sentinels] = 68 KB
{
    __shared__ _Float16 xbuf[2 * BATCH * XSTRIDE];   // ~65 KB, double-buffered
    __shared__ float    gbuf[2 * BATCH * GSTRIDE];   // ~8.5 KB, double-buffered

    const int tid  = threadIdx.x;
    const int wg   = blockIdx.x;
    const int lane = tid & 63;
    const int wave = tid >> 6;
    const int mt   = wave & 1;
    const int nt   = wave >> 1;
    const int row  = mt * 16 + (lane & 15);
    const int kq   = lane >> 4;

    u64* const sent = hrec + 2 * RECS_PER_PARITY;

    // ---- elementwise identity ---------------------------------------------
    const int eb   = tid >> 3;          // batch 0..31
    const int ej   = tid & 7;           // local h-col 0..7
    const int ecol = wg * HC + ej;

    // producer record index (4xf16 records): record covers global cols
    // wg*8 + (ej>>2)*4 .. +3 of batch eb.
    const int widx = (wg >> 2) * 256 + (ej >> 2) * 128 + eb * 4 + (wg & 3);

    float c_state = init_states[BATCH * H + eb * H + ecol];

    // ---- publish h0 FIRST (epoch 1, parity 0) so stragglers can proceed ---
    {
        _Float16 h0 = (_Float16)init_states[eb * H + ecol];
        u32 hu = (u32)__builtin_bit_cast(unsigned short, h0);
        u32 lo = hu | (__shfl_down(hu, 1) << 16);   // cols j, j+1
        u32 hi = __shfl_down(lo, 2);                // cols j+2, j+3
        if ((tid & 3) == 0)
            AT_ST_U64(&hrec[widx], (u64)lo | ((u64)hi << 32));
        if (lane == 0)
            AT_ST_REL_U64(&sent[wave * 64 + wg], 1ull);  // release: drains record stores
    }

    // ---- one-time: weight B-fragments into VGPRs --------------------------
    const int n_local = lane & 15;
    const int gi   = nt * 2 + (n_local >> 3);
    const int wcol = wg * HC + (n_local & 7);
    const float* Wmat = (gi == 0) ? Wi : (gi == 1) ? Wf : (gi == 2) ? Wc : Wo;
    const float* Umat = (gi == 0) ? Ui : (gi == 1) ? Uf : (gi == 2) ? Uc : Uo;

    half8 bfrag[32];                    // 128 VGPRs/lane, persistent
    #pragma unroll
    for (int kk = 0; kk < 16; ++kk) {
        #pragma unroll
        for (int jj = 0; jj < 8; ++jj) {
            int k = kk * 32 + kq * 8 + jj;
            bfrag[kk][jj]      = (_Float16)Wmat[k * H + wcol];
            bfrag[16 + kk][jj] = (_Float16)Umat[k * H + wcol];
        }
    }

    const float bi_v = bi[ecol], bf_v = bf[ecol], bc_v = bc[ecol], bo_v = bo[ecol];

    // ---- staging / x-MFMA helpers -----------------------------------------
    auto stage = [&](int t, int buf) {
        const int sb = tid >> 3;
        const int so = (tid & 7) * 4;
        const float* xr = x + ((size_t)sb * T_STEPS + t) * DIN;
        _Float16* xb = &xbuf[buf * (BATCH * XSTRIDE)];
        #pragma unroll
        for (int q = 0; q < 16; ++q) {
            int colq = so + q * 32;
            float4 v = *(const float4*)(xr + colq);
            half4v hv = { (_Float16)v.x, (_Float16)v.y,
                          (_Float16)v.z, (_Float16)v.w };
            *(half4v*)&xb[sb * XSTRIDE + colq] = hv;
        }
    };
    auto xmm = [&](int buf) -> f32x4 {
        f32x4 ax  = {0.f, 0.f, 0.f, 0.f};
        f32x4 ax2 = {0.f, 0.f, 0.f, 0.f};
        const _Float16* xr2 = &xbuf[buf * (BATCH * XSTRIDE) + row * XSTRIDE + kq * 8];
        #pragma unroll
        for (int kk = 0; kk < 16; kk += 2) {
            half8 a0 = *(const half8*)(xr2 + kk * 32);
            half8 a1 = *(const half8*)(xr2 + (kk + 1) * 32);
            ax  = __builtin_amdgcn_mfma_f32_16x16x32_f16(a0, bfrag[kk],     ax,  0, 0, 0);
            ax2 = __builtin_amdgcn_mfma_f32_16x16x32_f16(a1, bfrag[kk + 1], ax2, 0, 0, 0);
        }
        #pragma unroll
        for (int r = 0; r < 4; ++r) ax[r] += ax2[r];
        return ax;
    };

    // ---- prologue: stage x0,x1; x-MFMA(0). No grid barrier needed. --------
    stage(0, 0);
    stage(1, 1);
    __syncthreads();
    f32x4 acc_x = xmm(0);

    // consumer record base index (u64 units, without kk/s/parity)
    const int ridx_base = row * 4 + kq;

    // ---- main recurrence --------------------------------------------------
    for (int t = 0; t < T_STEPS; ++t) {
        const u64* rb = hrec + (size_t)(t & 1) * RECS_PER_PARITY;
        const u64* sp = sent + (size_t)(t & 1) * SENT_PER_PARITY + mt * 2 * 64;
        const u64 target = (u64)(t + 1);

        // cheap spin: 2 coalesced sentinel loads + __all per attempt.
        // Wave collectively covers waves {mt*2, mt*2+1} of all 64 WGs —
        // exactly the producers of the rows this wave consumes.
        {
            unsigned spins = 0;
            for (;;) {
                u64 s0 = AT_LD_U64(&sp[lane]);
                u64 s1 = AT_LD_U64(&sp[64 + lane]);
                if (__all((s0 == target) & (s1 == target))) break;
                if (++spins > 1000000u) break;   // safety valve
            }
        }

        // one-shot validated data load: 32 x 8B, fully coalesced
        // (per (kk,s) instruction the wave touches one contiguous 512B run)
        u64 rec[32];
        #pragma unroll
        for (int kk = 0; kk < 16; ++kk) {
            rec[kk * 2]     = AT_LD_U64(&rb[kk * 256 +       ridx_base]);
            rec[kk * 2 + 1] = AT_LD_U64(&rb[kk * 256 + 128 + ridx_base]);
        }

        // h-half matmul from registers
        float* gb = &gbuf[(t & 1) * (BATCH * GSTRIDE)];
        {
            f32x4 acc  = acc_x;
            f32x4 acc2 = {0.f, 0.f, 0.f, 0.f};
            #pragma unroll
            for (int kk = 0; kk < 16; kk += 2) {
                union { u64 q[2]; half8 h; } a0, a1;
                a0.q[0] = rec[kk * 2];     a0.q[1] = rec[kk * 2 + 1];
                a1.q[0] = rec[kk * 2 + 2]; a1.q[1] = rec[kk * 2 + 3];
                acc  = __builtin_amdgcn_mfma_f32_16x16x32_f16(a0.h, bfrag[16 + kk],     acc,  0, 0, 0);
                acc2 = __builtin_amdgcn_mfma_f32_16x16x32_f16(a1.h, bfrag[16 + kk + 1], acc2, 0, 0, 0);
            }
            #pragma unroll
            for (int r = 0; r < 4; ++r) {
                // C/D layout: col = lane&15, row = (lane>>4)*4 + r
                gb[(mt * 16 + kq * 4 + r) * GSTRIDE + nt * 16 + n_local] =
                    acc[r] + acc2[r];
            }
        }
        __syncthreads();   // the ONLY barrier per step (also the throttle anchor)

        // elementwise gates + state update + immediate h publish
        float h_val;
        {
            float pi = gb[eb * GSTRIDE + ej]      + bi_v;
            float pf = gb[eb * GSTRIDE + 8 + ej]  + bf_v;
            float pg = gb[eb * GSTRIDE + 16 + ej] + bc_v;
            float po = gb[eb * GSTRIDE + 24 + ej] + bo_v;
            float ig = sigmoidf_(pi);
            float fg = sigmoidf_(pf);
            float gg = tanhf_(pg);
            float og = sigmoidf_(po);
            c_state  = fg * c_state + ig * gg;
            h_val    = og * tanhf_(c_state);

            if (t + 1 < T_STEPS) {
                _Float16 hh = (_Float16)h_val;
                u32 hu = (u32)__builtin_bit_cast(unsigned short, hh);
                u32 lo = hu | (__shfl_down(hu, 1) << 16);
                u32 hi = __shfl_down(lo, 2);
                const size_t p1 = (size_t)((t + 1) & 1);
                if ((tid & 3) == 0)
                    AT_ST_U64(&hrec[p1 * RECS_PER_PARITY + widx],
                              (u64)lo | ((u64)hi << 32));
                // per-wave release sentinel: vmcnt(0) drain is wave-wide,
                // so this wave's 16 record stores are LLC-visible first.
                if (lane == 0)
                    AT_ST_REL_U64(&sent[p1 * SENT_PER_PARITY + wave * 64 + wg],
                                  (u64)(t + 2));
            }
        }

        // ---- off-critical-path tail (overlaps other WGs' latency) ---------
        out[((size_t)eb * T_STEPS + t) * H + ecol] = h_val;
        if (t + 1 < T_STEPS) {
            acc_x = xmm((t + 1) & 1);                 // staged last iteration
            if (t + 2 < T_STEPS) stage(t + 2, t & 1); // buffer read 2 steps on
        }
    }
}

extern "C" void kernel_launch(void* const* d_in, const int* in_sizes, int n_in,
                              void* d_out, int out_size, void* d_ws, size_t ws_size,
                              hipStream_t stream) {
    const float* x           = (const float*)d_in[0];
    const float* init_states = (const float*)d_in[1];
    const float* Wi = (const float*)d_in[2];
    const float* Ui = (const float*)d_in[3];
    const float* bi = (const float*)d_in[4];
    const float* Wf = (const float*)d_in[5];
    const float* Uf = (const float*)d_in[6];
    const float* bf = (const float*)d_in[7];
    const float* Wc = (const float*)d_in[8];
    const float* Uc = (const float*)d_in[9];
    const float* bc = (const float*)d_in[10];
    const float* Wo = (const float*)d_in[11];
    const float* Uo = (const float*)d_in[12];
    const float* bo = (const float*)d_in[13];
    float* out = (float*)d_out;

    // ws: [2 x 4096 x 8B records][2 x 256 x 8B sentinels] = 68 KB. No memset:
    // sentinels are validated by exact-match epochs (0xAAAA... poison never
    // matches), and the harness re-poisons ws before every launch so no
    // stale epochs from a prior replay can match either.
    u64* hrec = (u64*)d_ws;

    lstm_persistent<<<dim3(NWG), dim3(256), 0, stream>>>(
        x, init_states, Wi, Ui, bi, Wf, Uf, bf, Wc, Uc, bc, Wo, Uo, bo,
        out, hrec);
}

// Round 2
// 5237.609 us; speedup vs baseline: 1.2948x; 1.2948x over previous
//
#include <hip/hip_runtime.h>

// Two-phase persistent LSTM for MI355X.  B=32, T=1024, D_IN=512, H=512.
//
// R6: hoist the non-recurrent half out of the serial loop.
//   kernel 0: x f32 -> f16 convert (32 MB) into ws.
//   kernel 1: pre-gate GEMM  preg[t][gate][hcol][b] = x_t @ W_gate + bias
//             (256 WGs, all CUs, W-slices in VGPRs, LDS-staged x, proven
//             stage/xmm fragment math from the R4 kernel).
//   kernel 2: recurrence = R4 kernel minus ALL x machinery. The h exchange
//             reverts to R4's self-validating records (R5 post-mortem:
//             sentinel handshake added ~2 serialized LLC hops/step and
//             regressed 29%; the polling load must BE the data load).
//             MFMA accumulator is initialized straight from a prefetched
//             dwordx4 of preg in MFMA C-layout (bias folded in phase 1).
// Falls back to the single-kernel R4 path when ws is too small.

#define T_STEPS 1024
#define BATCH   32
#define DIN     512
#define H       512
#define NWG     64
#define HC      8
#define XSTRIDE 520        // f16 elems; 1040B row = bank offset 4 -> 2-way max (free)
#define GSTRIDE 34         // padded f32 row stride of LDS gate tile
#define RECS_PER_PARITY 8192   // 16 kk * 512   (R4 record format)

typedef _Float16 half8  __attribute__((ext_vector_type(8)));
typedef _Float16 half4v __attribute__((ext_vector_type(4)));
typedef float    f32x4  __attribute__((ext_vector_type(4)));
typedef unsigned long long u64;
typedef unsigned int       u32;

#define AT_LD_U64(p)   __hip_atomic_load((const u64*)(p), __ATOMIC_RELAXED, __HIP_MEMORY_SCOPE_AGENT)
#define AT_ST_U64(p,v) __hip_atomic_store((u64*)(p), (v), __ATOMIC_RELAXED, __HIP_MEMORY_SCOPE_AGENT)

__device__ __forceinline__ float sigmoidf_(float x) {
    return 1.0f / (1.0f + __expf(-x));
}
__device__ __forceinline__ float tanhf_(float x) {
    return 1.0f - 2.0f / (1.0f + __expf(2.0f * x));
}

// ======================= kernel 0: x -> f16 =============================
__global__ void xconvert(const float4* __restrict__ xin,
                         half4v* __restrict__ xout, int n4) {
    int i = blockIdx.x * blockDim.x + threadIdx.x;
    int stride = gridDim.x * blockDim.x;
    for (; i < n4; i += stride) {
        float4 v = xin[i];
        half4v h = { (_Float16)v.x, (_Float16)v.y,
                     (_Float16)v.z, (_Float16)v.w };
        xout[i] = h;
    }
}

// ======================= kernel 1: pre-gate GEMM ========================
// Grid: 256 WGs = 32 col-blocks (cb: 16 h-cols x 4 gates = 64 gate-cols)
//               x  8 t-ranges  (tq: 128 steps).
// Per wave: mt = m-half (16 batch rows), ng -> gates {ng*2, ng*2+1};
// per lane B-frags bfrag[2][16] (128 VGPRs). Output written with bias
// folded, in layout preg[t][gi][hcol][b] (b fastest -> one dwordx4/lane).
__global__ __launch_bounds__(256, 1) void lstm_pregate(
    const _Float16* __restrict__ x16,
    const float* __restrict__ Wi, const float* __restrict__ Wf,
    const float* __restrict__ Wc, const float* __restrict__ Wo,
    const float* __restrict__ bi, const float* __restrict__ bf,
    const float* __restrict__ bc, const float* __restrict__ bo,
    float* __restrict__ preg)
{
    __shared__ _Float16 xbuf[2 * BATCH * XSTRIDE];   // ~65 KB, double-buffered

    const int tid  = threadIdx.x;
    const int wg   = blockIdx.x;
    const int cb   = wg & 31;          // col-block: h-cols [cb*16, cb*16+16)
    const int tq   = wg >> 5;          // t-range  : [tq*128, tq*128+128)
    const int t0   = tq * 128;
    const int lane = tid & 63;
    const int wave = tid >> 6;
    const int mt   = wave & 1;
    const int ng   = wave >> 1;        // gates ng*2, ng*2+1
    const int n_local = lane & 15;
    const int kq   = lane >> 4;
    const int row  = mt * 16 + n_local;
    const int hcol = cb * 16 + n_local;

    // ---- one-time: W B-fragments into VGPRs (2 gates x 16 kk) ----------
    half8 bfrag[32];
    float bv[2];
    #pragma unroll
    for (int nn = 0; nn < 2; ++nn) {
        const int gi = ng * 2 + nn;
        const float* Wmat = (gi == 0) ? Wi : (gi == 1) ? Wf : (gi == 2) ? Wc : Wo;
        const float* bvec = (gi == 0) ? bi : (gi == 1) ? bf : (gi == 2) ? bc : bo;
        bv[nn] = bvec[hcol];
        #pragma unroll
        for (int kk = 0; kk < 16; ++kk) {
            #pragma unroll
            for (int jj = 0; jj < 8; ++jj) {
                int k = kk * 32 + kq * 8 + jj;
                bfrag[nn * 16 + kk][jj] = (_Float16)Wmat[k * H + hcol];
            }
        }
    }

    // ---- x staging (f16 source: straight copies, no cvt) ---------------
    auto stage = [&](int t, int buf) {
        const int sb = tid >> 3;            // batch row 0..31
        const int so = (tid & 7) * 8;       // 8 f16 per load, 8 loads/thread
        const _Float16* xr = x16 + ((size_t)sb * T_STEPS + t) * DIN;
        _Float16* xb = &xbuf[buf * (BATCH * XSTRIDE) + sb * XSTRIDE];
        #pragma unroll
        for (int q = 0; q < 8; ++q) {
            int colq = so + q * 64;
            *(half8*)&xb[colq] = *(const half8*)(xr + colq);
        }
    };

    stage(t0, 0);
    stage(t0 + 1, 1);
    __syncthreads();

    for (int lt = 0; lt < 128; ++lt) {
        const int t = t0 + lt;
        f32x4 a0 = {0.f, 0.f, 0.f, 0.f};
        f32x4 a1 = {0.f, 0.f, 0.f, 0.f};
        const _Float16* xr2 =
            &xbuf[(lt & 1) * (BATCH * XSTRIDE) + row * XSTRIDE + kq * 8];
        #pragma unroll
        for (int kk = 0; kk < 16; ++kk) {
            half8 av = *(const half8*)(xr2 + kk * 32);
            a0 = __builtin_amdgcn_mfma_f32_16x16x32_f16(av, bfrag[kk],      a0, 0, 0, 0);
            a1 = __builtin_amdgcn_mfma_f32_16x16x32_f16(av, bfrag[16 + kk], a1, 0, 0, 0);
        }
        #pragma unroll
        for (int r = 0; r < 4; ++r) { a0[r] += bv[0]; a1[r] += bv[1]; }

        // C/D layout: col = n_local (-> hcol), row = mt*16 + kq*4 + r (-> b)
        const size_t base =
            ((size_t)t * 2048 + (size_t)(ng * 2) * 512 + hcol) * 32
            + mt * 16 + kq * 4;
        *(f32x4*)&preg[base]            = a0;
        *(f32x4*)&preg[base + 512 * 32] = a1;   // gate gi+1

        __syncthreads();
        if (lt + 2 < 128) stage(t0 + lt + 2, lt & 1);
    }
}

// ======================= kernel 2: recurrence ===========================
// R4 kernel with all x machinery removed. Exchange protocol is R4's
// self-validating 8B records {epoch(hi32) | 2xf16(lo32)}, double-buffered
// by parity; the polling load IS the data load (1 LLC hop). Overwrite
// throttle: a WG can't run 2 steps ahead (see R4 header comment).
__global__ __launch_bounds__(256, 1) void lstm_recur(
    const float* __restrict__ init_states,
    const float* __restrict__ preg,     // [T][4][512][32] f32, bias folded
    float* __restrict__ out,
    u64* __restrict__ hrec)             // 2 parities x 8192 records x 8B
{
    __shared__ float gbuf[2 * BATCH * GSTRIDE];   // ~8.5 KB, double-buffered

    const int tid  = threadIdx.x;
    const int wg   = blockIdx.x;
    const int lane = tid & 63;
    const int wave = tid >> 6;
    const int mt   = wave & 1;
    const int nt   = wave >> 1;
    const int row  = mt * 16 + (lane & 15);
    const int kq   = lane >> 4;

    // ---- elementwise identity ------------------------------------------
    const int eb   = tid >> 3;
    const int ej   = tid & 7;
    const int ecol = wg * HC + ej;

    // ---- publish h0 FIRST (epoch 1, parity 0) --------------------------
    float c_state = init_states[BATCH * H + eb * H + ecol];
    {
        _Float16 h0 = (_Float16)init_states[eb * H + ecol];
        u32 hu  = (u32)__builtin_bit_cast(unsigned short, h0);
        u32 oth = __shfl_down(hu, 1);
        if ((tid & 1) == 0) {
            const int ridx = (wg >> 2) * 512 + (ej >> 1) * 128 + eb * 4 + (wg & 3);
            AT_ST_U64(&hrec[ridx], ((u64)1u << 32) | (u64)(hu | (oth << 16)));
        }
    }

    // ---- one-time: U B-fragments into VGPRs ----------------------------
    const int n_local = lane & 15;
    const int gi   = nt * 2 + (n_local >> 3);
    const int wcol = wg * HC + (n_local & 7);
    const float* Umat = (gi == 0) ? ((const float*)nullptr) : nullptr; // placeholder
    (void)Umat;

    half8 bfrag[16];
    // Umat selection done below (needs params) — passed via preg? No:
    // U matrices come in as kernel args in the fallback; here we take them
    // from constant pointers set up by the launcher (see extra params).
    // -- replaced: U pointers are passed as explicit args (see signature v2)
    // (kept single-signature: see lstm_recur_impl below)
    (void)bfrag;
    // This kernel body is defined in lstm_recur2 (with U args). Never launched.
}

// Actual recurrence kernel (with U pointers).
__global__ __launch_bounds__(256, 1) void lstm_recur2(
    const float* __restrict__ init_states,
    const float* __restrict__ Ui, const float* __restrict__ Uf,
    const float* __restrict__ Uc, const float* __restrict__ Uo,
    const float* __restrict__ preg,     // [T][4][512][32] f32, bias folded
    float* __restrict__ out,
    u64* __restrict__ hrec)
{
    __shared__ float gbuf[2 * BATCH * GSTRIDE];

    const int tid  = threadIdx.x;
    const int wg   = blockIdx.x;
    const int lane = tid & 63;
    const int wave = tid >> 6;
    const int mt   = wave & 1;
    const int nt   = wave >> 1;
    const int row  = mt * 16 + (lane & 15);
    const int kq   = lane >> 4;

    const int eb   = tid >> 3;
    const int ej   = tid & 7;
    const int ecol = wg * HC + ej;

    float c_state = init_states[BATCH * H + eb * H + ecol];
    {
        _Float16 h0 = (_Float16)init_states[eb * H + ecol];
        u32 hu  = (u32)__builtin_bit_cast(unsigned short, h0);
        u32 oth = __shfl_down(hu, 1);
        if ((tid & 1) == 0) {
            const int ridx = (wg >> 2) * 512 + (ej >> 1) * 128 + eb * 4 + (wg & 3);
            AT_ST_U64(&hrec[ridx], ((u64)1u << 32) | (u64)(hu | (oth << 16)));
        }
    }

    const int n_local = lane & 15;
    const int gi   = nt * 2 + (n_local >> 3);
    const int wcol = wg * HC + (n_local & 7);
    const float* Umat = (gi == 0) ? Ui : (gi == 1) ? Uf : (gi == 2) ? Uc : Uo;

    half8 bfrag[16];                    // 64 VGPRs/lane, persistent
    #pragma unroll
    for (int kk = 0; kk < 16; ++kk) {
        #pragma unroll
        for (int jj = 0; jj < 8; ++jj) {
            int k = kk * 32 + kq * 8 + jj;
            bfrag[kk][jj] = (_Float16)Umat[k * H + wcol];
        }
    }

    // pre-gate in MFMA C-layout: one dwordx4/lane/step, prefetched 1 ahead
    const size_t pgbase =
        ((size_t)gi * 512 + wcol) * 32 + mt * 16 + kq * 4;
    f32x4 pg = *(const f32x4*)&preg[pgbase];           // t = 0

    const int ridx_base = row * 4 + kq;
    const int widx = (wg >> 2) * 512 + (ej >> 1) * 128 + eb * 4 + (wg & 3);

    for (int t = 0; t < T_STEPS; ++t) {
        const u64* rb = hrec + (size_t)(t & 1) * RECS_PER_PARITY;
        const u32 target = (u32)(t + 1);

        // poll-load the 64 self-validating records (R4 verbatim)
        u64 rec[64];
        unsigned spins = 0;
        for (;;) {
            #pragma unroll
            for (int kk = 0; kk < 16; ++kk) {
                #pragma unroll
                for (int s = 0; s < 4; ++s)
                    rec[kk * 4 + s] = AT_LD_U64(&rb[kk * 512 + s * 128 + ridx_base]);
            }
            int ok = 1;
            #pragma unroll
            for (int i = 0; i < 64; ++i)
                ok &= ((u32)(rec[i] >> 32) == target);
            if (__all(ok)) break;
            if (++spins > 300000u) break;   // safety valve
        }

        // prefetch next step's pre-gate (consumed after next poll)
        f32x4 pgn = pg;
        if (t + 1 < T_STEPS)
            pgn = *(const f32x4*)&preg[(size_t)(t + 1) * 65536 + pgbase];

        // h-half matmul from registers; acc starts at pre-gate (x@W + b)
        float* gb = &gbuf[(t & 1) * (BATCH * GSTRIDE)];
        {
            f32x4 acc  = pg;
            f32x4 acc2 = {0.f, 0.f, 0.f, 0.f};
            #pragma unroll
            for (int kk = 0; kk < 16; kk += 2) {
                union { u32 d[4]; half8 h; } a0, a1;
                #pragma unroll
                for (int s = 0; s < 4; ++s) {
                    a0.d[s] = (u32)rec[kk * 4 + s];
                    a1.d[s] = (u32)rec[(kk + 1) * 4 + s];
                }
                acc  = __builtin_amdgcn_mfma_f32_16x16x32_f16(a0.h, bfrag[kk],     acc,  0, 0, 0);
                acc2 = __builtin_amdgcn_mfma_f32_16x16x32_f16(a1.h, bfrag[kk + 1], acc2, 0, 0, 0);
            }
            #pragma unroll
            for (int r = 0; r < 4; ++r) {
                gb[(mt * 16 + kq * 4 + r) * GSTRIDE + nt * 16 + n_local] =
                    acc[r] + acc2[r];
            }
        }
        __syncthreads();   // the ONLY barrier per step

        float h_val;
        {
            float pi = gb[eb * GSTRIDE + ej];
            float pf = gb[eb * GSTRIDE + 8 + ej];
            float pg_ = gb[eb * GSTRIDE + 16 + ej];
            float po = gb[eb * GSTRIDE + 24 + ej];
            float ig = sigmoidf_(pi);
            float fg = sigmoidf_(pf);
            float gg = tanhf_(pg_);
            float og = sigmoidf_(po);
            c_state  = fg * c_state + ig * gg;
            h_val    = og * tanhf_(c_state);

            if (t + 1 < T_STEPS) {
                _Float16 hh = (_Float16)h_val;
                u32 hu  = (u32)__builtin_bit_cast(unsigned short, hh);
                u32 oth = __shfl_down(hu, 1);
                if ((tid & 1) == 0) {
                    AT_ST_U64(&hrec[(size_t)((t + 1) & 1) * RECS_PER_PARITY + widx],
                              ((u64)(u32)(t + 2) << 32) | (u64)(hu | (oth << 16)));
                }
            }
        }

        out[((size_t)eb * T_STEPS + t) * H + ecol] = h_val;
        pg = pgn;
    }
}

// ======================= fallback: R4 single kernel =====================
__global__ __launch_bounds__(256, 1) void lstm_persistent_fb(
    const float* __restrict__ x,
    const float* __restrict__ init_states,
    const float* __restrict__ Wi, const float* __restrict__ Ui, const float* __restrict__ bi,
    const float* __restrict__ Wf, const float* __restrict__ Uf, const float* __restrict__ bf,
    const float* __restrict__ Wc, const float* __restrict__ Uc, const float* __restrict__ bc,
    const float* __restrict__ Wo, const float* __restrict__ Uo, const float* __restrict__ bo,
    float* __restrict__ out,
    u64* __restrict__ hrec)
{
    __shared__ _Float16 xbuf[2 * BATCH * XSTRIDE];
    __shared__ float    gbuf[2 * BATCH * GSTRIDE];

    const int tid  = threadIdx.x;
    const int wg   = blockIdx.x;
    const int lane = tid & 63;
    const int wave = tid >> 6;
    const int mt   = wave & 1;
    const int nt   = wave >> 1;
    const int row  = mt * 16 + (lane & 15);
    const int kq   = lane >> 4;

    const int eb   = tid >> 3;
    const int ej   = tid & 7;
    const int ecol = wg * HC + ej;

    float c_state = init_states[BATCH * H + eb * H + ecol];
    {
        _Float16 h0 = (_Float16)init_states[eb * H + ecol];
        u32 hu  = (u32)__builtin_bit_cast(unsigned short, h0);
        u32 oth = __shfl_down(hu, 1);
        if ((tid & 1) == 0) {
            const int ridx = (wg >> 2) * 512 + (ej >> 1) * 128 + eb * 4 + (wg & 3);
            AT_ST_U64(&hrec[ridx], ((u64)1u << 32) | (u64)(hu | (oth << 16)));
        }
    }

    const int n_local = lane & 15;
    const int gi   = nt * 2 + (n_local >> 3);
    const int wcol = wg * HC + (n_local & 7);
    const float* Wmat = (gi == 0) ? Wi : (gi == 1) ? Wf : (gi == 2) ? Wc : Wo;
    const float* Umat = (gi == 0) ? Ui : (gi == 1) ? Uf : (gi == 2) ? Uc : Uo;

    half8 bfrag[32];
    #pragma unroll
    for (int kk = 0; kk < 16; ++kk) {
        #pragma unroll
        for (int jj = 0; jj < 8; ++jj) {
            int k = kk * 32 + kq * 8 + jj;
            bfrag[kk][jj]      = (_Float16)Wmat[k * H + wcol];
            bfrag[16 + kk][jj] = (_Float16)Umat[k * H + wcol];
        }
    }

    const float bi_v = bi[ecol], bf_v = bf[ecol], bc_v = bc[ecol], bo_v = bo[ecol];

    auto stage = [&](int t, int buf) {
        const int sb = tid >> 3;
        const int so = (tid & 7) * 4;
        const float* xr = x + ((size_t)sb * T_STEPS + t) * DIN;
        _Float16* xb = &xbuf[buf * (BATCH * XSTRIDE)];
        #pragma unroll
        for (int q = 0; q < 16; ++q) {
            int colq = so + q * 32;
            float4 v = *(const float4*)(xr + colq);
            half4v hv = { (_Float16)v.x, (_Float16)v.y,
                          (_Float16)v.z, (_Float16)v.w };
            *(half4v*)&xb[sb * XSTRIDE + colq] = hv;
        }
    };
    auto xmm = [&](int buf) -> f32x4 {
        f32x4 ax  = {0.f, 0.f, 0.f, 0.f};
        f32x4 ax2 = {0.f, 0.f, 0.f, 0.f};
        const _Float16* xr2 = &xbuf[buf * (BATCH * XSTRIDE) + row * XSTRIDE + kq * 8];
        #pragma unroll
        for (int kk = 0; kk < 16; kk += 2) {
            half8 a0 = *(const half8*)(xr2 + kk * 32);
            half8 a1 = *(const half8*)(xr2 + (kk + 1) * 32);
            ax  = __builtin_amdgcn_mfma_f32_16x16x32_f16(a0, bfrag[kk],     ax,  0, 0, 0);
            ax2 = __builtin_amdgcn_mfma_f32_16x16x32_f16(a1, bfrag[kk + 1], ax2, 0, 0, 0);
        }
        #pragma unroll
        for (int r = 0; r < 4; ++r) ax[r] += ax2[r];
        return ax;
    };

    stage(0, 0);
    stage(1, 1);
    __syncthreads();
    f32x4 acc_x = xmm(0);

    const int ridx_base = row * 4 + kq;
    const int widx = (wg >> 2) * 512 + (ej >> 1) * 128 + eb * 4 + (wg & 3);

    for (int t = 0; t < T_STEPS; ++t) {
        const u64* rb = hrec + (size_t)(t & 1) * RECS_PER_PARITY;
        const u32 target = (u32)(t + 1);

        u64 rec[64];
        unsigned spins = 0;
        for (;;) {
            #pragma unroll
            for (int kk = 0; kk < 16; ++kk) {
                #pragma unroll
                for (int s = 0; s < 4; ++s)
                    rec[kk * 4 + s] = AT_LD_U64(&rb[kk * 512 + s * 128 + ridx_base]);
            }
            int ok = 1;
            #pragma unroll
            for (int i = 0; i < 64; ++i)
                ok &= ((u32)(rec[i] >> 32) == target);
            if (__all(ok)) break;
            if (++spins > 300000u) break;
        }

        float* gb = &gbuf[(t & 1) * (BATCH * GSTRIDE)];
        {
            f32x4 acc  = acc_x;
            f32x4 acc2 = {0.f, 0.f, 0.f, 0.f};
            #pragma unroll
            for (int kk = 0; kk < 16; kk += 2) {
                union { u32 d[4]; half8 h; } a0, a1;
                #pragma unroll
                for (int s = 0; s < 4; ++s) {
                    a0.d[s] = (u32)rec[kk * 4 + s];
                    a1.d[s] = (u32)rec[(kk + 1) * 4 + s];
                }
                acc  = __builtin_amdgcn_mfma_f32_16x16x32_f16(a0.h, bfrag[16 + kk],     acc,  0, 0, 0);
                acc2 = __builtin_amdgcn_mfma_f32_16x16x32_f16(a1.h, bfrag[16 + kk + 1], acc2, 0, 0, 0);
            }
            #pragma unroll
            for (int r = 0; r < 4; ++r) {
                gb[(mt * 16 + kq * 4 + r) * GSTRIDE + nt * 16 + n_local] =
                    acc[r] + acc2[r];
            }
        }
        __syncthreads();

        float h_val;
        {
            float pi = gb[eb * GSTRIDE + ej]      + bi_v;
            float pf = gb[eb * GSTRIDE + 8 + ej]  + bf_v;
            float pg = gb[eb * GSTRIDE + 16 + ej] + bc_v;
            float po = gb[eb * GSTRIDE + 24 + ej] + bo_v;
            float ig = sigmoidf_(pi);
            float fg = sigmoidf_(pf);
            float gg = tanhf_(pg);
            float og = sigmoidf_(po);
            c_state  = fg * c_state + ig * gg;
            h_val    = og * tanhf_(c_state);

            if (t + 1 < T_STEPS) {
                _Float16 hh = (_Float16)h_val;
                u32 hu  = (u32)__builtin_bit_cast(unsigned short, hh);
                u32 oth = __shfl_down(hu, 1);
                if ((tid & 1) == 0) {
                    AT_ST_U64(&hrec[(size_t)((t + 1) & 1) * RECS_PER_PARITY + widx],
                              ((u64)(u32)(t + 2) << 32) | (u64)(hu | (oth << 16)));
                }
            }
        }

        out[((size_t)eb * T_STEPS + t) * H + ecol] = h_val;
        if (t + 1 < T_STEPS) {
            acc_x = xmm((t + 1) & 1);
            if (t + 2 < T_STEPS) stage(t + 2, t & 1);
        }
    }
}

// ======================= launcher ======================================
extern "C" void kernel_launch(void* const* d_in, const int* in_sizes, int n_in,
                              void* d_out, int out_size, void* d_ws, size_t ws_size,
                              hipStream_t stream) {
    const float* x           = (const float*)d_in[0];
    const float* init_states = (const float*)d_in[1];
    const float* Wi = (const float*)d_in[2];
    const float* Ui = (const float*)d_in[3];
    const float* bi = (const float*)d_in[4];
    const float* Wf = (const float*)d_in[5];
    const float* Uf = (const float*)d_in[6];
    const float* bf = (const float*)d_in[7];
    const float* Wc = (const float*)d_in[8];
    const float* Uc = (const float*)d_in[9];
    const float* bc = (const float*)d_in[10];
    const float* Wo = (const float*)d_in[11];
    const float* Uo = (const float*)d_in[12];
    const float* bo = (const float*)d_in[13];
    float* out = (float*)d_out;

    const size_t PREG_BYTES = (size_t)1024 * 2048 * 32 * 4;   // 268 MB
    const size_t X16_BYTES  = (size_t)32 * 1024 * 512 * 2;    //  32 MB
    const size_t HREC_BYTES = (size_t)2 * RECS_PER_PARITY * 8; // 128 KB

    if (ws_size >= PREG_BYTES + X16_BYTES + HREC_BYTES) {
        float*    preg = (float*)d_ws;
        _Float16* x16  = (_Float16*)((char*)d_ws + PREG_BYTES);
        u64*      hrec = (u64*)((char*)d_ws + PREG_BYTES + X16_BYTES);

        xconvert<<<dim3(2048), dim3(256), 0, stream>>>(
            (const float4*)x, (half4v*)x16, 4194304);
        lstm_pregate<<<dim3(256), dim3(256), 0, stream>>>(
            x16, Wi, Wf, Wc, Wo, bi, bf, bc, bo, preg);
        lstm_recur2<<<dim3(NWG), dim3(256), 0, stream>>>(
            init_states, Ui, Uf, Uc, Uo, preg, out, hrec);
    } else {
        u64* hrec = (u64*)d_ws;
        lstm_persistent_fb<<<dim3(NWG), dim3(256), 0, stream>>>(
            x, init_states, Wi, Ui, bi, Wf, Uf, bf, Wc, Uc, bc, Wo, Uo, bo,
            out, hrec);
    }
}

// Round 4
// 4359.657 us; speedup vs baseline: 1.5555x; 1.2014x over previous
//
#include <hip/hip_runtime.h>

// Two-phase persistent LSTM for MI355X.  B=32, T=1024, D_IN=512, H=512.
//
// R8 = R7 with the pregate wave->gate bug fixed.  R7 launched pregate with
// 256 threads (4 waves) but mapped gsel = wave>>1 (0..1): gates 2,3 were
// never written and kept ws poison -> absmax ~1.0.  Fix: pregate runs with
// 512 threads = 8 waves; (mt, gsel) = (wave&1, wave>>1) covers 2 batch
// halves x 4 gates, ONE gate per wave.  INVARIANT: pregate wave count must
// equal 2*4; launch config and mapping change together.
//
// Structure (unchanged from R7):
//   pregate(chunk): 256 WGs x 512 thr.  preg[lt][gate][hcol][b] =
//     x_t @ W_g + b_g  (f32, MFMA C-layout, bias folded).
//   recur(chunk): 64 WGs x 256 thr, R4 kernel minus ALL x machinery.
//     h exchange = R4's self-validating 8B records {epoch|2xf16} (the
//     polling load IS the data load; R5 proved sentinel indirection adds
//     2 serialized LLC hops/step and regresses).  Epochs are GLOBAL step
//     numbers, monotone across chunks.  c_state persists in ws; MFMA acc
//     is seeded from one prefetched dwordx4 of preg.
//   Chunked over T so any ws_size works; falls back to R4 if ws < 4.4 MB.

#define T_STEPS 1024
#define BATCH   32
#define DIN     512
#define H       512
#define NWG     64
#define HC      8
#define XSTRIDE 520        // f16 elems; 1040B row = bank offset 4 -> 2-way max (free)
#define GSTRIDE 34         // padded f32 row stride of LDS gate tile
#define RECS_PER_PARITY 8192   // 16 kk * 512   (R4 record format)

typedef _Float16 half8  __attribute__((ext_vector_type(8)));
typedef _Float16 half4v __attribute__((ext_vector_type(4)));
typedef float    f32x4  __attribute__((ext_vector_type(4)));
typedef unsigned long long u64;
typedef unsigned int       u32;

#define AT_LD_U64(p)   __hip_atomic_load((const u64*)(p), __ATOMIC_RELAXED, __HIP_MEMORY_SCOPE_AGENT)
#define AT_ST_U64(p,v) __hip_atomic_store((u64*)(p), (v), __ATOMIC_RELAXED, __HIP_MEMORY_SCOPE_AGENT)

__device__ __forceinline__ float sigmoidf_(float x) {
    return 1.0f / (1.0f + __expf(-x));
}
__device__ __forceinline__ float tanhf_(float x) {
    return 1.0f - 2.0f / (1.0f + __expf(2.0f * x));
}

// ======================= kernel 1: pre-gate GEMM ========================
// Grid: 256 WGs x 512 threads = 32 col-blocks (cb: 16 h-cols) x 8 t-ranges.
// Waves (8): mt = wave&1 (batch half), gsel = wave>>1 (gate 0..3) — one
// gate per wave.  Output preg[lt][gate][hcol][b], b fastest, bias folded,
// exactly MFMA C-layout so recur seeds its accumulator with one dwordx4.
__global__ __launch_bounds__(512, 1) void lstm_pregate(
    const float* __restrict__ x,
    const float* __restrict__ Wi, const float* __restrict__ Wf,
    const float* __restrict__ Wc, const float* __restrict__ Wo,
    const float* __restrict__ bi, const float* __restrict__ bf,
    const float* __restrict__ bc, const float* __restrict__ bo,
    float* __restrict__ preg, int t0, int tc)
{
    __shared__ _Float16 xbuf[2 * BATCH * XSTRIDE];   // ~65 KB, double-buffered

    const int tid  = threadIdx.x;
    const int wg   = blockIdx.x;
    const int cb   = wg & 31;          // h-cols [cb*16, cb*16+16)
    const int tq   = wg >> 5;          // t-range within chunk
    const int tcq  = tc >> 3;          // steps per t-range (>= 2)
    const int tb   = t0 + tq * tcq;    // global first step of this WG
    const int lane = tid & 63;
    const int wave = tid >> 6;         // 0..7
    const int mt   = wave & 1;         // batch half
    const int gsel = wave >> 1;        // gate 0..3  (8 waves REQUIRED)
    const int n_local = lane & 15;
    const int kq   = lane >> 4;
    const int row  = mt * 16 + n_local;    // batch row for A-frag
    const int hcol = cb * 16 + n_local;

    const float* Wmat = (gsel == 0) ? Wi : (gsel == 1) ? Wf : (gsel == 2) ? Wc : Wo;
    const float* bvec = (gsel == 0) ? bi : (gsel == 1) ? bf : (gsel == 2) ? bc : bo;
    const float bv = bvec[hcol];

    // ---- one-time: W B-fragments into VGPRs (one gate, 16 kk) ----------
    half8 bfrag[16];
    #pragma unroll
    for (int kk = 0; kk < 16; ++kk) {
        #pragma unroll
        for (int jj = 0; jj < 8; ++jj) {
            int k = kk * 32 + kq * 8 + jj;
            bfrag[kk][jj] = (_Float16)Wmat[k * H + hcol];
        }
    }

    // ---- x staging (f32 -> f16), 512-thread version --------------------
    // 32 rows x 16 threads/row; each thread 8 float4 loads (stride 64 cols).
    auto stage = [&](int t, int buf) {
        const int sb = tid >> 4;            // batch row 0..31
        const int so = (tid & 15) * 4;
        const float* xr = x + ((size_t)sb * T_STEPS + t) * DIN;
        _Float16* xb = &xbuf[buf * (BATCH * XSTRIDE)];
        #pragma unroll
        for (int q = 0; q < 8; ++q) {
            int colq = so + q * 64;
            float4 v = *(const float4*)(xr + colq);
            half4v hv = { (_Float16)v.x, (_Float16)v.y,
                          (_Float16)v.z, (_Float16)v.w };
            *(half4v*)&xb[sb * XSTRIDE + colq] = hv;
        }
    };

    stage(tb, 0);
    stage(tb + 1, 1);
    __syncthreads();

    for (int lt = 0; lt < tcq; ++lt) {
        f32x4 a0 = {0.f, 0.f, 0.f, 0.f};
        f32x4 a1 = {0.f, 0.f, 0.f, 0.f};
        const _Float16* xr2 =
            &xbuf[(lt & 1) * (BATCH * XSTRIDE) + row * XSTRIDE + kq * 8];
        #pragma unroll
        for (int kk = 0; kk < 16; kk += 2) {
            half8 v0 = *(const half8*)(xr2 + kk * 32);
            half8 v1 = *(const half8*)(xr2 + (kk + 1) * 32);
            a0 = __builtin_amdgcn_mfma_f32_16x16x32_f16(v0, bfrag[kk],     a0, 0, 0, 0);
            a1 = __builtin_amdgcn_mfma_f32_16x16x32_f16(v1, bfrag[kk + 1], a1, 0, 0, 0);
        }
        f32x4 aw;
        #pragma unroll
        for (int r = 0; r < 4; ++r) aw[r] = a0[r] + a1[r] + bv;

        // C/D layout: col = n_local (-> hcol), row = kq*4 + r (-> batch
        // within half mt).  Chunk-local step index.
        const size_t base =
            (((size_t)(tb - t0 + lt) * 4 + gsel) * 512 + hcol) * 32
            + mt * 16 + kq * 4;
        *(f32x4*)&preg[base] = aw;

        __syncthreads();
        if (lt + 2 < tcq) stage(tb + lt + 2, lt & 1);
    }
}

// ======================= kernel 2: recurrence ===========================
__global__ __launch_bounds__(256, 1) void lstm_recur(
    const float* __restrict__ init_states,
    const float* __restrict__ Ui, const float* __restrict__ Uf,
    const float* __restrict__ Uc, const float* __restrict__ Uo,
    const float* __restrict__ preg,   // [tc][4][512][32] f32, bias folded
    float* __restrict__ out,
    u64* __restrict__ hrec,           // 2 parities x 8192 records
    float* __restrict__ cst,          // [32][512] persistent c-state
    int t0, int tc)
{
    __shared__ float gbuf[2 * BATCH * GSTRIDE];

    const int tid  = threadIdx.x;
    const int wg   = blockIdx.x;
    const int lane = tid & 63;
    const int wave = tid >> 6;
    const int mt   = wave & 1;
    const int nt   = wave >> 1;
    const int row  = mt * 16 + (lane & 15);
    const int kq   = lane >> 4;

    const int eb   = tid >> 3;
    const int ej   = tid & 7;
    const int ecol = wg * HC + ej;

    // c-state: from init on chunk 0, else from ws
    float c_state = (t0 == 0) ? init_states[BATCH * H + eb * H + ecol]
                              : cst[eb * H + ecol];

    // publish h0 (epoch 1, parity 0) only on chunk 0; later chunks rely on
    // the previous launch's final publish (global epochs are monotone).
    if (t0 == 0) {
        _Float16 h0 = (_Float16)init_states[eb * H + ecol];
        u32 hu  = (u32)__builtin_bit_cast(unsigned short, h0);
        u32 oth = __shfl_down(hu, 1);
        if ((tid & 1) == 0) {
            const int ridx = (wg >> 2) * 512 + (ej >> 1) * 128 + eb * 4 + (wg & 3);
            AT_ST_U64(&hrec[ridx], ((u64)1u << 32) | (u64)(hu | (oth << 16)));
        }
    }

    // ---- one-time: U B-fragments into VGPRs ----------------------------
    const int n_local = lane & 15;
    const int gi   = nt * 2 + (n_local >> 3);      // gate 0..3 (nt in 0..1)
    const int wcol = wg * HC + (n_local & 7);
    const float* Umat = (gi == 0) ? Ui : (gi == 1) ? Uf : (gi == 2) ? Uc : Uo;

    half8 bfrag[16];                    // 64 VGPRs/lane, persistent
    #pragma unroll
    for (int kk = 0; kk < 16; ++kk) {
        #pragma unroll
        for (int jj = 0; jj < 8; ++jj) {
            int k = kk * 32 + kq * 8 + jj;
            bfrag[kk][jj] = (_Float16)Umat[k * H + wcol];
        }
    }

    // pre-gate in MFMA C-layout: one dwordx4/lane/step, prefetched 1 ahead
    const size_t pgbase =
        ((size_t)gi * 512 + wcol) * 32 + mt * 16 + kq * 4;
    f32x4 pg = *(const f32x4*)&preg[pgbase];           // lt = 0

    const int ridx_base = row * 4 + kq;
    const int widx = (wg >> 2) * 512 + (ej >> 1) * 128 + eb * 4 + (wg & 3);

    for (int lt = 0; lt < tc; ++lt) {
        const int gt = t0 + lt;                        // global step
        const u64* rb = hrec + (size_t)(gt & 1) * RECS_PER_PARITY;
        const u32 target = (u32)(gt + 1);

        // poll-load the 64 self-validating records (R4 verbatim)
        u64 rec[64];
        unsigned spins = 0;
        for (;;) {
            #pragma unroll
            for (int kk = 0; kk < 16; ++kk) {
                #pragma unroll
                for (int s = 0; s < 4; ++s)
                    rec[kk * 4 + s] = AT_LD_U64(&rb[kk * 512 + s * 128 + ridx_base]);
            }
            int ok = 1;
            #pragma unroll
            for (int i = 0; i < 64; ++i)
                ok &= ((u32)(rec[i] >> 32) == target);
            if (__all(ok)) break;
            if (++spins > 300000u) break;   // safety valve
        }

        // prefetch next step's pre-gate (consumed after next poll)
        f32x4 pgn = pg;
        if (lt + 1 < tc)
            pgn = *(const f32x4*)&preg[(size_t)(lt + 1) * 65536 + pgbase];

        // h-half matmul from registers; acc starts at pre-gate (x@W + b)
        float* gb = &gbuf[(gt & 1) * (BATCH * GSTRIDE)];
        {
            f32x4 acc  = pg;
            f32x4 acc2 = {0.f, 0.f, 0.f, 0.f};
            #pragma unroll
            for (int kk = 0; kk < 16; kk += 2) {
                union { u32 d[4]; half8 h; } a0, a1;
                #pragma unroll
                for (int s = 0; s < 4; ++s) {
                    a0.d[s] = (u32)rec[kk * 4 + s];
                    a1.d[s] = (u32)rec[(kk + 1) * 4 + s];
                }
                acc  = __builtin_amdgcn_mfma_f32_16x16x32_f16(a0.h, bfrag[kk],     acc,  0, 0, 0);
                acc2 = __builtin_amdgcn_mfma_f32_16x16x32_f16(a1.h, bfrag[kk + 1], acc2, 0, 0, 0);
            }
            #pragma unroll
            for (int r = 0; r < 4; ++r) {
                gb[(mt * 16 + kq * 4 + r) * GSTRIDE + nt * 16 + n_local] =
                    acc[r] + acc2[r];
            }
        }
        __syncthreads();   // the ONLY barrier per step

        float h_val;
        {
            float pi  = gb[eb * GSTRIDE + ej];
            float pf  = gb[eb * GSTRIDE + 8 + ej];
            float pgg = gb[eb * GSTRIDE + 16 + ej];
            float po  = gb[eb * GSTRIDE + 24 + ej];
            float ig = sigmoidf_(pi);
            float fg = sigmoidf_(pf);
            float gg = tanhf_(pgg);
            float og = sigmoidf_(po);
            c_state  = fg * c_state + ig * gg;
            h_val    = og * tanhf_(c_state);

            if (gt + 1 < T_STEPS) {
                _Float16 hh = (_Float16)h_val;
                u32 hu  = (u32)__builtin_bit_cast(unsigned short, hh);
                u32 oth = __shfl_down(hu, 1);
                if ((tid & 1) == 0) {
                    AT_ST_U64(&hrec[(size_t)((gt + 1) & 1) * RECS_PER_PARITY + widx],
                              ((u64)(u32)(gt + 2) << 32) | (u64)(hu | (oth << 16)));
                }
            }
        }

        out[((size_t)eb * T_STEPS + gt) * H + ecol] = h_val;
        pg = pgn;
    }

    // persist c-state for the next chunk launch
    cst[eb * H + ecol] = c_state;
}

// ======================= fallback: R4 single kernel =====================
__global__ __launch_bounds__(256, 1) void lstm_persistent_fb(
    const float* __restrict__ x,
    const float* __restrict__ init_states,
    const float* __restrict__ Wi, const float* __restrict__ Ui, const float* __restrict__ bi,
    const float* __restrict__ Wf, const float* __restrict__ Uf, const float* __restrict__ bf,
    const float* __restrict__ Wc, const float* __restrict__ Uc, const float* __restrict__ bc,
    const float* __restrict__ Wo, const float* __restrict__ Uo, const float* __restrict__ bo,
    float* __restrict__ out,
    u64* __restrict__ hrec)
{
    __shared__ _Float16 xbuf[2 * BATCH * XSTRIDE];
    __shared__ float    gbuf[2 * BATCH * GSTRIDE];

    const int tid  = threadIdx.x;
    const int wg   = blockIdx.x;
    const int lane = tid & 63;
    const int wave = tid >> 6;
    const int mt   = wave & 1;
    const int nt   = wave >> 1;
    const int row  = mt * 16 + (lane & 15);
    const int kq   = lane >> 4;

    const int eb   = tid >> 3;
    const int ej   = tid & 7;
    const int ecol = wg * HC + ej;

    float c_state = init_states[BATCH * H + eb * H + ecol];
    {
        _Float16 h0 = (_Float16)init_states[eb * H + ecol];
        u32 hu  = (u32)__builtin_bit_cast(unsigned short, h0);
        u32 oth = __shfl_down(hu, 1);
        if ((tid & 1) == 0) {
            const int ridx = (wg >> 2) * 512 + (ej >> 1) * 128 + eb * 4 + (wg & 3);
            AT_ST_U64(&hrec[ridx], ((u64)1u << 32) | (u64)(hu | (oth << 16)));
        }
    }

    const int n_local = lane & 15;
    const int gi   = nt * 2 + (n_local >> 3);
    const int wcol = wg * HC + (n_local & 7);
    const float* Wmat = (gi == 0) ? Wi : (gi == 1) ? Wf : (gi == 2) ? Wc : Wo;
    const float* Umat = (gi == 0) ? Ui : (gi == 1) ? Uf : (gi == 2) ? Uc : Uo;

    half8 bfrag[32];
    #pragma unroll
    for (int kk = 0; kk < 16; ++kk) {
        #pragma unroll
        for (int jj = 0; jj < 8; ++jj) {
            int k = kk * 32 + kq * 8 + jj;
            bfrag[kk][jj]      = (_Float16)Wmat[k * H + wcol];
            bfrag[16 + kk][jj] = (_Float16)Umat[k * H + wcol];
        }
    }

    const float bi_v = bi[ecol], bf_v = bf[ecol], bc_v = bc[ecol], bo_v = bo[ecol];

    auto stage = [&](int t, int buf) {
        const int sb = tid >> 3;
        const int so = (tid & 7) * 4;
        const float* xr = x + ((size_t)sb * T_STEPS + t) * DIN;
        _Float16* xb = &xbuf[buf * (BATCH * XSTRIDE)];
        #pragma unroll
        for (int q = 0; q < 16; ++q) {
            int colq = so + q * 32;
            float4 v = *(const float4*)(xr + colq);
            half4v hv = { (_Float16)v.x, (_Float16)v.y,
                          (_Float16)v.z, (_Float16)v.w };
            *(half4v*)&xb[sb * XSTRIDE + colq] = hv;
        }
    };
    auto xmm = [&](int buf) -> f32x4 {
        f32x4 ax  = {0.f, 0.f, 0.f, 0.f};
        f32x4 ax2 = {0.f, 0.f, 0.f, 0.f};
        const _Float16* xr2 = &xbuf[buf * (BATCH * XSTRIDE) + row * XSTRIDE + kq * 8];
        #pragma unroll
        for (int kk = 0; kk < 16; kk += 2) {
            half8 a0 = *(const half8*)(xr2 + kk * 32);
            half8 a1 = *(const half8*)(xr2 + (kk + 1) * 32);
            ax  = __builtin_amdgcn_mfma_f32_16x16x32_f16(a0, bfrag[kk],     ax,  0, 0, 0);
            ax2 = __builtin_amdgcn_mfma_f32_16x16x32_f16(a1, bfrag[kk + 1], ax2, 0, 0, 0);
        }
        #pragma unroll
        for (int r = 0; r < 4; ++r) ax[r] += ax2[r];
        return ax;
    };

    stage(0, 0);
    stage(1, 1);
    __syncthreads();
    f32x4 acc_x = xmm(0);

    const int ridx_base = row * 4 + kq;
    const int widx = (wg >> 2) * 512 + (ej >> 1) * 128 + eb * 4 + (wg & 3);

    for (int t = 0; t < T_STEPS; ++t) {
        const u64* rb = hrec + (size_t)(t & 1) * RECS_PER_PARITY;
        const u32 target = (u32)(t + 1);

        u64 rec[64];
        unsigned spins = 0;
        for (;;) {
            #pragma unroll
            for (int kk = 0; kk < 16; ++kk) {
                #pragma unroll
                for (int s = 0; s < 4; ++s)
                    rec[kk * 4 + s] = AT_LD_U64(&rb[kk * 512 + s * 128 + ridx_base]);
            }
            int ok = 1;
            #pragma unroll
            for (int i = 0; i < 64; ++i)
                ok &= ((u32)(rec[i] >> 32) == target);
            if (__all(ok)) break;
            if (++spins > 300000u) break;
        }

        float* gb = &gbuf[(t & 1) * (BATCH * GSTRIDE)];
        {
            f32x4 acc  = acc_x;
            f32x4 acc2 = {0.f, 0.f, 0.f, 0.f};
            #pragma unroll
            for (int kk = 0; kk < 16; kk += 2) {
                union { u32 d[4]; half8 h; } a0, a1;
                #pragma unroll
                for (int s = 0; s < 4; ++s) {
                    a0.d[s] = (u32)rec[kk * 4 + s];
                    a1.d[s] = (u32)rec[(kk + 1) * 4 + s];
                }
                acc  = __builtin_amdgcn_mfma_f32_16x16x32_f16(a0.h, bfrag[16 + kk],     acc,  0, 0, 0);
                acc2 = __builtin_amdgcn_mfma_f32_16x16x32_f16(a1.h, bfrag[16 + kk + 1], acc2, 0, 0, 0);
            }
            #pragma unroll
            for (int r = 0; r < 4; ++r) {
                gb[(mt * 16 + kq * 4 + r) * GSTRIDE + nt * 16 + n_local] =
                    acc[r] + acc2[r];
            }
        }
        __syncthreads();

        float h_val;
        {
            float pi = gb[eb * GSTRIDE + ej]      + bi_v;
            float pf = gb[eb * GSTRIDE + 8 + ej]  + bf_v;
            float pg = gb[eb * GSTRIDE + 16 + ej] + bc_v;
            float po = gb[eb * GSTRIDE + 24 + ej] + bo_v;
            float ig = sigmoidf_(pi);
            float fg = sigmoidf_(pf);
            float gg = tanhf_(pg);
            float og = sigmoidf_(po);
            c_state  = fg * c_state + ig * gg;
            h_val    = og * tanhf_(c_state);

            if (t + 1 < T_STEPS) {
                _Float16 hh = (_Float16)h_val;
                u32 hu  = (u32)__builtin_bit_cast(unsigned short, hh);
                u32 oth = __shfl_down(hu, 1);
                if ((tid & 1) == 0) {
                    AT_ST_U64(&hrec[(size_t)((t + 1) & 1) * RECS_PER_PARITY + widx],
                              ((u64)(u32)(t + 2) << 32) | (u64)(hu | (oth << 16)));
                }
            }
        }

        out[((size_t)eb * T_STEPS + t) * H + ecol] = h_val;
        if (t + 1 < T_STEPS) {
            acc_x = xmm((t + 1) & 1);
            if (t + 2 < T_STEPS) stage(t + 2, t & 1);
        }
    }
}

// ======================= launcher ======================================
extern "C" void kernel_launch(void* const* d_in, const int* in_sizes, int n_in,
                              void* d_out, int out_size, void* d_ws, size_t ws_size,
                              hipStream_t stream) {
    const float* x           = (const float*)d_in[0];
    const float* init_states = (const float*)d_in[1];
    const float* Wi = (const float*)d_in[2];
    const float* Ui = (const float*)d_in[3];
    const float* bi = (const float*)d_in[4];
    const float* Wf = (const float*)d_in[5];
    const float* Uf = (const float*)d_in[6];
    const float* bf = (const float*)d_in[7];
    const float* Wc = (const float*)d_in[8];
    const float* Uc = (const float*)d_in[9];
    const float* bc = (const float*)d_in[10];
    const float* Wo = (const float*)d_in[11];
    const float* Uo = (const float*)d_in[12];
    const float* bo = (const float*)d_in[13];
    float* out = (float*)d_out;

    const size_t HREC_BYTES = (size_t)2 * RECS_PER_PARITY * 8;  // 128 KB
    const size_t CST_BYTES  = (size_t)BATCH * H * 4;            //  64 KB

    // largest chunk size whose preg buffer fits the workspace
    static const int cands[] = {1024, 512, 256, 128, 64, 32, 16};
    int tc = 0;
    size_t preg_bytes = 0;
    for (int i = 0; i < 7; ++i) {
        size_t pb = (size_t)cands[i] * 2048 * 32 * 4;   // [tc][4][512][32] f32
        if (ws_size >= pb + HREC_BYTES + CST_BYTES) { tc = cands[i]; preg_bytes = pb; break; }
    }

    if (tc > 0) {
        float* preg = (float*)d_ws;
        u64*   hrec = (u64*)((char*)d_ws + preg_bytes);
        float* cst  = (float*)((char*)d_ws + preg_bytes + HREC_BYTES);

        const int nchunks = T_STEPS / tc;
        for (int c = 0; c < nchunks; ++c) {
            lstm_pregate<<<dim3(256), dim3(512), 0, stream>>>(
                x, Wi, Wf, Wc, Wo, bi, bf, bc, bo, preg, c * tc, tc);
            lstm_recur<<<dim3(NWG), dim3(256), 0, stream>>>(
                init_states, Ui, Uf, Uc, Uo, preg, out, hrec, cst, c * tc, tc);
        }
    } else {
        u64* hrec = (u64*)d_ws;
        lstm_persistent_fb<<<dim3(NWG), dim3(256), 0, stream>>>(
            x, init_states, Wi, Ui, bi, Wf, Uf, bf, Wc, Uc, bc, Wo, Uo, bo,
            out, hrec);
    }
}